// Round 8
// baseline (170.789 us; speedup 1.0000x reference)
//
#include <hip/hip_runtime.h>

// DIAGNOSTIC ROUND: measure the gather's true FETCH_SIZE/WRITE_SIZE.
// The harness's 1 GiB poison fills (151-158 us) crowd our 66 us kernel out
// of the top-5 counter table, so the read-miss volume has never been
// observed. This version does the patch copy 3x inside one dispatch
// (pass 0 -> d_out, passes 1-2 -> d_ws scratch) so the dispatch runs
// ~150-200 us and surfaces in top-5. Per-block re-reads in passes 1-2 are
// L1/L2-hot (same 64 KB the block just read), so FETCH_SIZE ~= single-pass
// read-miss volume. WRITE_SIZE ~= 3 x 268 MB sanity-checks the denominator.
//
// Schedule = proven R4 base: 32-row band counting sort + chunked XCD
// swizzle + nt dwordx4 stores. Fallback (small ws) = exact R4 single-pass.

#define IMG_W   4096
#define PATCH_W 128
#define F4_PER_PATCH (PATCH_W * PATCH_W / 4)   // 4096
#define BLOCK   256
#define NB      128   // row-band buckets (p0 >> 5)

typedef float f32x4 __attribute__((ext_vector_type(4)));

__global__ __launch_bounds__(1024) void order_kernel(
    const int* __restrict__ positions, int* __restrict__ order, int N)
{
    __shared__ int hist[NB];
    __shared__ int base[NB];
    const int tid = threadIdx.x;

    for (int b = tid; b < NB; b += blockDim.x) hist[b] = 0;
    __syncthreads();

    for (int i = tid; i < N; i += blockDim.x)
        atomicAdd(&hist[positions[2 * i] >> 5], 1);
    __syncthreads();

    if (tid == 0) {
        int s = 0;
        for (int b = 0; b < NB; ++b) { base[b] = s; s += hist[b]; }
    }
    __syncthreads();

    for (int b = tid; b < NB; b += blockDim.x) hist[b] = base[b];
    __syncthreads();

    for (int i = tid; i < N; i += blockDim.x) {
        const int slot = atomicAdd(&hist[positions[2 * i] >> 5], 1);
        order[slot] = i;
    }
}

// Diagnostic: 3 passes per patch. dst0 = real output; dst1/dst2 = scratch.
__global__ __launch_bounds__(BLOCK) void patch_gather3_kernel(
    const float* __restrict__ images,
    const int*   __restrict__ positions,
    const int*   __restrict__ order,
    float*       __restrict__ dst0,
    float*       __restrict__ dst1,
    float*       __restrict__ dst2,
    int N)
{
    int slot = blockIdx.x;
    if ((N & 7) == 0) {
        const int nper = N >> 3;
        slot = (blockIdx.x & 7) * nper + (blockIdx.x >> 3);
    }
    const int n  = order ? order[slot] : slot;
    const int p0 = positions[2 * n];
    const int p1 = positions[2 * n + 1];

    const float* srcp = images + (size_t)p0 * IMG_W + p1;
    const size_t off  = (size_t)n * (PATCH_W * PATCH_W);

    #pragma unroll
    for (int it = 0; it < F4_PER_PATCH / BLOCK; ++it) {
        const int i  = it * BLOCK + threadIdx.x;
        const int r  = i >> 5;
        const int c  = (i & 31) << 2;
        const size_t po = (size_t)r * PATCH_W + c;

        const float* s = srcp + (size_t)r * IMG_W + c;
        f32x4 v;
        v.x = s[0];
        v.y = s[1];
        v.z = s[2];
        v.w = s[3];
        __builtin_nontemporal_store(v, reinterpret_cast<f32x4*>(dst0 + off + po));
        __builtin_nontemporal_store(v, reinterpret_cast<f32x4*>(dst1 + off + po));
        __builtin_nontemporal_store(v, reinterpret_cast<f32x4*>(dst2 + off + po));
    }
}

// Fallback: exact R4 single-pass (66.1 us proven).
__global__ __launch_bounds__(BLOCK) void patch_gather_kernel(
    const float* __restrict__ images,
    const int*   __restrict__ positions,
    const int*   __restrict__ order,
    float*       __restrict__ out,
    int N)
{
    int slot = blockIdx.x;
    if ((N & 7) == 0) {
        const int nper = N >> 3;
        slot = (blockIdx.x & 7) * nper + (blockIdx.x >> 3);
    }
    const int n  = order ? order[slot] : slot;
    const int p0 = positions[2 * n];
    const int p1 = positions[2 * n + 1];

    const float* srcp = images + (size_t)p0 * IMG_W + p1;
    float*       dst  = out + (size_t)n * (PATCH_W * PATCH_W);

    #pragma unroll
    for (int it = 0; it < F4_PER_PATCH / BLOCK; ++it) {
        const int i  = it * BLOCK + threadIdx.x;
        const int r  = i >> 5;
        const int c  = (i & 31) << 2;
        const float* s = srcp + (size_t)r * IMG_W + c;
        f32x4 v;
        v.x = s[0]; v.y = s[1]; v.z = s[2]; v.w = s[3];
        __builtin_nontemporal_store(
            v, reinterpret_cast<f32x4*>(dst + (size_t)r * PATCH_W + c));
    }
}

extern "C" void kernel_launch(void* const* d_in, const int* in_sizes, int n_in,
                              void* d_out, int out_size, void* d_ws, size_t ws_size,
                              hipStream_t stream) {
    const float* images    = (const float*)d_in[0];
    const int*   positions = (const int*)d_in[1];
    float* out = (float*)d_out;

    const int N = in_sizes[1] / 2;   // 4096 patches

    const size_t order_bytes = (size_t)N * sizeof(int);
    const size_t copy_bytes  = (size_t)N * PATCH_W * PATCH_W * sizeof(float); // 268 MB
    const size_t copy_off    = 32u << 20;                                      // 32 MB
    const size_t need3       = copy_off + 2 * copy_bytes;                      // ~570 MB

    int* order = nullptr;
    if (ws_size >= order_bytes) {
        order = (int*)d_ws;
        order_kernel<<<1, 1024, 0, stream>>>(positions, order, N);
    }

    if (ws_size >= need3) {
        float* ws1 = (float*)((char*)d_ws + copy_off);
        float* ws2 = (float*)((char*)d_ws + copy_off + copy_bytes);
        patch_gather3_kernel<<<N, BLOCK, 0, stream>>>(
            images, positions, order, out, ws1, ws2, N);
    } else {
        patch_gather_kernel<<<N, BLOCK, 0, stream>>>(images, positions, order, out, N);
    }
}

// Round 9
// 89.973 us; speedup vs baseline: 1.8982x; 1.8982x over previous
//
#include <hip/hip_runtime.h>

// Patch gather: out[n, r, c] = images[(p0[n] + r) * W + p1[n] + c]
// Fixed geometry: H = W = 4096, width = 128, N = 4096.
//
// R4 base (band-sort + chunked XCD swizzle + dwordx4) with ONE change vs the
// 65.6 us kernel: PLAIN stores instead of non-temporal. R8 diagnostic showed
// reads are fully cache-absorbed (FETCH ~37 MB) while writes ran at only
// ~4.2-4.7 TB/s vs the 7 TB/s the harness memsets prove on this same output
// buffer -> the nt flag (added under a falsified theory) is the suspected
// write-throughput limiter.
//
//  1) order_kernel: single-block counting sort by 32-row band (p0>>5, 128
//     buckets) into d_ws.
//  2) patch_gather_kernel: one block per patch in band-sorted order, chunked
//     XCD swizzle, plain dwordx4 stores.

#define IMG_W   4096
#define PATCH_W 128
#define F4_PER_PATCH (PATCH_W * PATCH_W / 4)   // 4096
#define BLOCK   256
#define NB      128   // row-band buckets (p0 >> 5, p0 < 4096)

typedef float f32x4 __attribute__((ext_vector_type(4)));

__global__ __launch_bounds__(1024) void order_kernel(
    const int* __restrict__ positions, int* __restrict__ order, int N)
{
    __shared__ int hist[NB];
    __shared__ int base[NB];
    const int tid = threadIdx.x;

    for (int b = tid; b < NB; b += blockDim.x) hist[b] = 0;
    __syncthreads();

    for (int i = tid; i < N; i += blockDim.x)
        atomicAdd(&hist[positions[2 * i] >> 5], 1);
    __syncthreads();

    if (tid == 0) {
        int s = 0;
        for (int b = 0; b < NB; ++b) { base[b] = s; s += hist[b]; }
    }
    __syncthreads();

    for (int b = tid; b < NB; b += blockDim.x) hist[b] = base[b];
    __syncthreads();

    for (int i = tid; i < N; i += blockDim.x) {
        const int slot = atomicAdd(&hist[positions[2 * i] >> 5], 1);
        order[slot] = i;
    }
}

__global__ __launch_bounds__(BLOCK) void patch_gather_kernel(
    const float* __restrict__ images,
    const int*   __restrict__ positions,
    const int*   __restrict__ order,     // may be null -> identity order
    float*       __restrict__ out,
    int N)
{
    int slot = blockIdx.x;
    if ((N & 7) == 0) {
        // chunked XCD swizzle: same-(blockIdx&7) blocks share an XCD; give
        // each XCD a contiguous chunk of the band-sorted patch list.
        const int nper = N >> 3;
        slot = (blockIdx.x & 7) * nper + (blockIdx.x >> 3);
    }
    const int n  = order ? order[slot] : slot;
    const int p0 = positions[2 * n];
    const int p1 = positions[2 * n + 1];

    const float* srcp = images + (size_t)p0 * IMG_W + p1;
    float*       dst  = out + (size_t)n * (PATCH_W * PATCH_W);

    #pragma unroll
    for (int it = 0; it < F4_PER_PATCH / BLOCK; ++it) {
        const int i  = it * BLOCK + threadIdx.x;   // float4 index within patch
        const int r  = i >> 5;                     // i / 32 (32 float4 per row)
        const int c  = (i & 31) << 2;              // (i % 32) * 4

        const float* s = srcp + (size_t)r * IMG_W + c;
        f32x4 v;
        v.x = s[0];
        v.y = s[1];
        v.z = s[2];
        v.w = s[3];
        *reinterpret_cast<f32x4*>(dst + (size_t)r * PATCH_W + c) = v;
    }
}

extern "C" void kernel_launch(void* const* d_in, const int* in_sizes, int n_in,
                              void* d_out, int out_size, void* d_ws, size_t ws_size,
                              hipStream_t stream) {
    const float* images    = (const float*)d_in[0];
    const int*   positions = (const int*)d_in[1];
    float* out = (float*)d_out;

    const int N = in_sizes[1] / 2;   // 4096 patches

    int* order = nullptr;
    if (ws_size >= (size_t)N * sizeof(int)) {
        order = (int*)d_ws;
        order_kernel<<<1, 1024, 0, stream>>>(positions, order, N);
    }
    patch_gather_kernel<<<N, BLOCK, 0, stream>>>(images, positions, order, out, N);
}

// Round 10
// 89.539 us; speedup vs baseline: 1.9074x; 1.0049x over previous
//
#include <hip/hip_runtime.h>

// Patch gather, ROW-MAJOR SCATTER restructure.
// out[n, r-p0, c] = images[r, p1+c] for each patch n overlapping image row r.
//
// Why: R8/R9 pinned the patch-major schedule between two cache artifacts:
//   plain stores  -> write-allocations flush the image from cache, reads miss
//                    (~570 MB HBM, 90 us)
//   nt stores     -> reads stay cached (FETCH ~37 MB) but the nt drain path
//                    caps at ~4.7 TB/s (66 us)
// Fix: dedup reads in SOFTWARE. Each block owns 4 image rows (read from HBM
// exactly once into LDS -> no cache-retention dependence at all) and scatters
// them into all overlapping patches with PLAIN stores (memset path, 7 TB/s).
// Compulsory traffic only: 64 MB read + 268 MB write.
//
//  1) order_kernel (1 block, 1024 thr): exact counting sort of patches by p0
//     (4096 bins) -> rec[] {n,p0,p1}, plus prefix row_start[4097].
//  2) row_scatter_kernel (1024 blocks): block b stages image rows
//     [4b, 4b+4) into LDS (64 KB), then for each patch with
//     p0 in [4b-127, 4b+3] writes the 1..4 overlapping patch rows
//     (512 B per row per wave, contiguous up to 2 KB per patch).

#define IMG_W   4096
#define IMG_H   4096
#define PATCH_W 128
#define BLOCK   256
#define ROWS    4
#define NBINS   4096

typedef float f32x4 __attribute__((ext_vector_type(4)));

__global__ __launch_bounds__(1024) void order_kernel(
    const int* __restrict__ positions,
    int4*      __restrict__ rec,
    int*       __restrict__ row_start,   // NBINS+1 ints
    int N)
{
    __shared__ int hist[NBINS];      // 16 KB
    __shared__ int partial[1024];    // 4 KB
    const int tid = threadIdx.x;

    #pragma unroll
    for (int j = 0; j < NBINS / 1024; ++j) hist[tid + j * 1024] = 0;
    __syncthreads();

    for (int i = tid; i < N; i += 1024) {
        const int2 p = ((const int2*)positions)[i];
        atomicAdd(&hist[p.x], 1);
    }
    __syncthreads();

    // two-level exclusive scan: thread t owns bins [4t, 4t+4)
    const int b0 = tid * (NBINS / 1024);
    int s = 0;
    #pragma unroll
    for (int j = 0; j < NBINS / 1024; ++j) s += hist[b0 + j];
    partial[tid] = s;
    __syncthreads();

    for (int off = 1; off < 1024; off <<= 1) {
        const int v   = partial[tid];
        const int add = (tid >= off) ? partial[tid - off] : 0;
        __syncthreads();
        partial[tid] = v + add;
        __syncthreads();
    }

    int running = partial[tid] - s;  // exclusive base of this thread's bins
    #pragma unroll
    for (int j = 0; j < NBINS / 1024; ++j) {
        const int b   = b0 + j;
        const int cnt = hist[b];
        row_start[b] = running;
        hist[b]      = running;      // becomes scatter cursor
        running += cnt;
    }
    if (tid == 1023) row_start[NBINS] = running;   // == N
    __syncthreads();

    for (int i = tid; i < N; i += 1024) {
        const int2 p = ((const int2*)positions)[i];
        const int slot = atomicAdd(&hist[p.x], 1);
        rec[slot] = make_int4(i, p.x, p.y, 0);
    }
}

__global__ __launch_bounds__(BLOCK) void row_scatter_kernel(
    const float* __restrict__ images,
    const int4*  __restrict__ rec,
    const int*   __restrict__ row_start,
    float*       __restrict__ out)
{
    __shared__ float rows[ROWS * IMG_W];   // 64 KB -> 2 blocks/CU
    const int base_r = blockIdx.x * ROWS;

    // stage 4 image rows (block-exclusive: each image byte read once, ever)
    {
        const f32x4* src = (const f32x4*)(images + (size_t)base_r * IMG_W);
        f32x4*       dst = (f32x4*)rows;
        #pragma unroll
        for (int it = 0; it < ROWS * IMG_W / 4 / BLOCK; ++it)   // 16 iters
            dst[it * BLOCK + threadIdx.x] = src[it * BLOCK + threadIdx.x];
    }
    __syncthreads();

    // candidate patches: p0 in [base_r-127, base_r+ROWS-1]
    const int s0 = row_start[max(0, base_r - (PATCH_W - 1))];
    const int s1 = row_start[base_r + ROWS];

    const int wid  = threadIdx.x >> 6;    // wave id 0..3
    const int lane = threadIdx.x & 63;

    for (int idx = s0 + wid; idx < s1; idx += BLOCK / 64) {
        const int4 rr = rec[idx];
        const int n = rr.x, p0 = rr.y, p1 = rr.z;
        const int rlo = max(p0, base_r);
        const int rhi = min(p0 + PATCH_W, base_r + ROWS);

        float*       dstp = out + (size_t)n * (PATCH_W * PATCH_W) + 2 * lane;
        const float* lds  = rows + p1 + 2 * lane;

        for (int r = rlo; r < rhi; ++r) {
            const int lo = (r - base_r) * IMG_W;
            float2 v;
            v.x = lds[lo];
            v.y = lds[lo + 1];
            // plain store: 64 lanes x 8 B = 512 B contiguous per row
            *reinterpret_cast<float2*>(dstp + (size_t)(r - p0) * PATCH_W) = v;
        }
    }
}

// Fallback (tiny ws): identity-order nt gather (R3 path, ~89 us, correct).
__global__ __launch_bounds__(BLOCK) void patch_gather_kernel(
    const float* __restrict__ images,
    const int*   __restrict__ positions,
    float*       __restrict__ out)
{
    const int n  = blockIdx.x;
    const int p0 = positions[2 * n];
    const int p1 = positions[2 * n + 1];

    const float* srcp = images + (size_t)p0 * IMG_W + p1;
    float*       dst  = out + (size_t)n * (PATCH_W * PATCH_W);

    #pragma unroll
    for (int it = 0; it < (PATCH_W * PATCH_W / 4) / BLOCK; ++it) {
        const int i = it * BLOCK + threadIdx.x;
        const int r = i >> 5;
        const int c = (i & 31) << 2;
        const float* s = srcp + (size_t)r * IMG_W + c;
        f32x4 v;
        v.x = s[0]; v.y = s[1]; v.z = s[2]; v.w = s[3];
        __builtin_nontemporal_store(
            v, reinterpret_cast<f32x4*>(dst + (size_t)r * PATCH_W + c));
    }
}

extern "C" void kernel_launch(void* const* d_in, const int* in_sizes, int n_in,
                              void* d_out, int out_size, void* d_ws, size_t ws_size,
                              hipStream_t stream) {
    const float* images    = (const float*)d_in[0];
    const int*   positions = (const int*)d_in[1];
    float* out = (float*)d_out;

    const int N = in_sizes[1] / 2;   // 4096 patches

    const size_t rec_off = 32768;    // row_start (16.4 KB) lives at offset 0
    const size_t need    = rec_off + (size_t)N * sizeof(int4);

    if (ws_size >= need) {
        int*  row_start = (int*)d_ws;
        int4* rec       = (int4*)((char*)d_ws + rec_off);
        order_kernel<<<1, 1024, 0, stream>>>(positions, rec, row_start, N);
        row_scatter_kernel<<<IMG_H / ROWS, BLOCK, 0, stream>>>(
            images, rec, row_start, out);
    } else {
        patch_gather_kernel<<<N, BLOCK, 0, stream>>>(images, positions, out);
    }
}

// Round 11
// 89.458 us; speedup vs baseline: 1.9091x; 1.0009x over previous
//
#include <hip/hip_runtime.h>

// Patch gather: out[n, r, c] = images[(p0[n] + r) * W + p1[n] + c]
// Fixed geometry: H = W = 4096, width = 128, N = 4096.
//
// R4 base (band-sort + chunked XCD swizzle + dwordx4) with ONE change:
// HYBRID store policy. Measured corners: nt+sort=66us, plain+sort=90us,
// and R8 diag showed nt keeps reads cached (FETCH 37MB) but drains at only
// ~4.3-4.7 TB/s, while plain stores drain at 7 TB/s (memset-proven) but
// allocate 268MB of unique L3 lines -> 268+64 > 256MB L3 -> image evicted,
// reads miss (capacity effect, which is why sorting didn't save plain).
// Hybrid: even-index patches use PLAIN stores (134MB allocated; 134+64=198MB
// < 256MB L3 so the image survives), odd-index patches use NT. Half the
// write volume moves to the fast drain path while reads stay cache-hit.
//
//  1) order_kernel: single-block counting sort by 32-row band (p0>>5).
//  2) patch_gather_kernel: one block per patch in band-sorted order, chunked
//     XCD swizzle; store flavor chosen per patch parity (wave-uniform).

#define IMG_W   4096
#define PATCH_W 128
#define F4_PER_PATCH (PATCH_W * PATCH_W / 4)   // 4096
#define BLOCK   256
#define NB      128   // row-band buckets (p0 >> 5, p0 < 4096)

typedef float f32x4 __attribute__((ext_vector_type(4)));

__global__ __launch_bounds__(1024) void order_kernel(
    const int* __restrict__ positions, int* __restrict__ order, int N)
{
    __shared__ int hist[NB];
    __shared__ int base[NB];
    const int tid = threadIdx.x;

    for (int b = tid; b < NB; b += blockDim.x) hist[b] = 0;
    __syncthreads();

    for (int i = tid; i < N; i += blockDim.x)
        atomicAdd(&hist[positions[2 * i] >> 5], 1);
    __syncthreads();

    if (tid == 0) {
        int s = 0;
        for (int b = 0; b < NB; ++b) { base[b] = s; s += hist[b]; }
    }
    __syncthreads();

    for (int b = tid; b < NB; b += blockDim.x) hist[b] = base[b];
    __syncthreads();

    for (int i = tid; i < N; i += blockDim.x) {
        const int slot = atomicAdd(&hist[positions[2 * i] >> 5], 1);
        order[slot] = i;
    }
}

__global__ __launch_bounds__(BLOCK) void patch_gather_kernel(
    const float* __restrict__ images,
    const int*   __restrict__ positions,
    const int*   __restrict__ order,     // may be null -> identity order
    float*       __restrict__ out,
    int N)
{
    int slot = blockIdx.x;
    if ((N & 7) == 0) {
        // chunked XCD swizzle: same-(blockIdx&7) blocks share an XCD; give
        // each XCD a contiguous chunk of the band-sorted patch list.
        const int nper = N >> 3;
        slot = (blockIdx.x & 7) * nper + (blockIdx.x >> 3);
    }
    const int n  = order ? order[slot] : slot;
    const int p0 = positions[2 * n];
    const int p1 = positions[2 * n + 1];

    const float* srcp = images + (size_t)p0 * IMG_W + p1;
    float*       dst  = out + (size_t)n * (PATCH_W * PATCH_W);

    const bool use_nt = (n & 1);   // wave-uniform: policy per patch

    if (use_nt) {
        #pragma unroll
        for (int it = 0; it < F4_PER_PATCH / BLOCK; ++it) {
            const int i  = it * BLOCK + threadIdx.x;
            const int r  = i >> 5;
            const int c  = (i & 31) << 2;
            const float* s = srcp + (size_t)r * IMG_W + c;
            f32x4 v;
            v.x = s[0]; v.y = s[1]; v.z = s[2]; v.w = s[3];
            __builtin_nontemporal_store(
                v, reinterpret_cast<f32x4*>(dst + (size_t)r * PATCH_W + c));
        }
    } else {
        #pragma unroll
        for (int it = 0; it < F4_PER_PATCH / BLOCK; ++it) {
            const int i  = it * BLOCK + threadIdx.x;
            const int r  = i >> 5;
            const int c  = (i & 31) << 2;
            const float* s = srcp + (size_t)r * IMG_W + c;
            f32x4 v;
            v.x = s[0]; v.y = s[1]; v.z = s[2]; v.w = s[3];
            *reinterpret_cast<f32x4*>(dst + (size_t)r * PATCH_W + c) = v;
        }
    }
}

extern "C" void kernel_launch(void* const* d_in, const int* in_sizes, int n_in,
                              void* d_out, int out_size, void* d_ws, size_t ws_size,
                              hipStream_t stream) {
    const float* images    = (const float*)d_in[0];
    const int*   positions = (const int*)d_in[1];
    float* out = (float*)d_out;

    const int N = in_sizes[1] / 2;   // 4096 patches

    int* order = nullptr;
    if (ws_size >= (size_t)N * sizeof(int)) {
        order = (int*)d_ws;
        order_kernel<<<1, 1024, 0, stream>>>(positions, order, N);
    }
    patch_gather_kernel<<<N, BLOCK, 0, stream>>>(images, positions, order, out, N);
}